// Round 1
// baseline (586.171 us; speedup 1.0000x reference)
//
#include <hip/hip_runtime.h>
#include <cstdint>
#include <cstddef>

#define N_NODES 1024
#define K_NEIGH 5
#define L_TIME  2016
#define PATCHSZ 12
#define EMBED   96
#define CINX    6            // (K_NEIGH+1)*IN_CH
#define P_CNT   168          // L_TIME / PATCHSZ
#define KDOT    72           // CINX*PATCHSZ

// ---------------- Threefry-2x32, JAX partitionable scheme ----------------
__device__ __forceinline__ uint32_t rotl32(uint32_t x, int r) {
  return (x << r) | (x >> (32 - r));
}

// key = (0, 42) from jax.random.key(42); returns x0^x1 (32-bit partitionable bits)
__device__ __forceinline__ uint32_t threefry_bits(uint32_t hi, uint32_t lo) {
  const uint32_t ks0 = 0u;
  const uint32_t ks1 = 42u;
  const uint32_t ks2 = ks0 ^ ks1 ^ 0x1BD11BDAu;
  uint32_t x0 = hi + ks0;
  uint32_t x1 = lo + ks1;
#define TF_ROUND(r) { x0 += x1; x1 = rotl32(x1, (r)); x1 ^= x0; }
  TF_ROUND(13) TF_ROUND(15) TF_ROUND(26) TF_ROUND(6)
  x0 += ks1; x1 += ks2 + 1u;
  TF_ROUND(17) TF_ROUND(29) TF_ROUND(16) TF_ROUND(24)
  x0 += ks2; x1 += ks0 + 2u;
  TF_ROUND(13) TF_ROUND(15) TF_ROUND(26) TF_ROUND(6)
  x0 += ks0; x1 += ks1 + 3u;
  TF_ROUND(17) TF_ROUND(29) TF_ROUND(16) TF_ROUND(24)
  x0 += ks1; x1 += ks2 + 4u;
  TF_ROUND(13) TF_ROUND(15) TF_ROUND(26) TF_ROUND(6)
  x0 += ks2; x1 += ks0 + 5u;
#undef TF_ROUND
  return x0 ^ x1;
}

// JAX uniform(minval=tiny, maxval=1) -> gumbel = -log(-log(u))
__device__ __forceinline__ float gumbel_from_bits(uint32_t bits) {
  float f = __uint_as_float((bits >> 9) | 0x3f800000u) - 1.0f;  // [0,1)
  f = fmaxf(f, 1.17549435e-38f);                                // minval=tiny
  return -logf(-logf(f));
}

// ---------------- Kernel 1: Gumbel-max neighbor sampling ----------------
// grid = N_NODES*K_NEIGH blocks, 256 threads. Row r = n*K + k.
// value[j] = log(adj[n][j]) + gumbel(flat index r*1024 + j); argmax (first max wins).
__global__ __launch_bounds__(256)
void sample_kernel(const float* __restrict__ adj, int* __restrict__ sampled) {
  const int row = blockIdx.x;           // 0 .. 5119
  const int n = row / K_NEIGH;
  const int tid = threadIdx.x;
  const uint32_t base = (uint32_t)row * (uint32_t)N_NODES;
  const float* arow = adj + (size_t)n * N_NODES;

  float best = -3.0e38f;
  int bestj = 0;
  for (int j = tid; j < N_NODES; j += 256) {
    uint32_t bits = threefry_bits(0u, base + (uint32_t)j);
    float v = logf(arow[j]) + gumbel_from_bits(bits);
    if (v > best) { best = v; bestj = j; }   // per-thread j increases -> first-max kept
  }
  // wave(64) reduction, tie -> lower index
  #pragma unroll
  for (int off = 32; off > 0; off >>= 1) {
    float ov = __shfl_down(best, off);
    int   oj = __shfl_down(bestj, off);
    if (ov > best || (ov == best && oj < bestj)) { best = ov; bestj = oj; }
  }
  __shared__ float sv[4];
  __shared__ int   sj[4];
  if ((tid & 63) == 0) { sv[tid >> 6] = best; sj[tid >> 6] = bestj; }
  __syncthreads();
  if (tid == 0) {
    #pragma unroll
    for (int wv = 1; wv < 4; ++wv) {
      if (sv[wv] > best || (sv[wv] == best && sj[wv] < bestj)) { best = sv[wv]; bestj = sj[wv]; }
    }
    sampled[row] = bestj;
  }
}

// ---------------- Kernel 2: gather + per-patch GEMM (Conv2d (12,1)/stride 12) ----
// grid = B*N blocks of 256 threads (4 waves). Wave w owns output channels
// [w*24, w*24+24); lane covers patch p = lane + 64*rep, rep<3.
// x (72 floats/patch) lives in VGPRs; weights broadcast from LDS.
__global__ __launch_bounds__(256)
void embed_kernel(const float* __restrict__ hist, const float* __restrict__ wgt,
                  const float* __restrict__ bias, const int* __restrict__ sampled,
                  float* __restrict__ out) {
  __shared__ __align__(16) float sw[EMBED * KDOT];   // 27648 B
  __shared__ float sb[EMBED];

  const int bn = blockIdx.x;          // b*1024 + n
  const int n  = bn & (N_NODES - 1);
  const int b  = bn >> 10;
  const int tid = threadIdx.x;

  // stage weights + bias (coalesced)
  for (int i = tid; i < EMBED * KDOT; i += 256) sw[i] = wgt[i];
  if (tid < EMBED) sb[tid] = bias[tid];

  // the 6 source rows: self + 5 sampled neighbors
  const float* rows[CINX];
  rows[0] = hist + (size_t)bn * L_TIME;
  #pragma unroll
  for (int k = 0; k < K_NEIGH; ++k) {
    int nb = sampled[n * K_NEIGH + k];
    rows[k + 1] = hist + ((size_t)b * N_NODES + nb) * L_TIME;
  }
  __syncthreads();

  const int wave = tid >> 6;
  const int lane = tid & 63;
  const int obase = wave * 24;
  float* outbn = out + (size_t)bn * EMBED * P_CNT;

  for (int rep = 0; rep < 3; ++rep) {
    const int p = lane + (rep << 6);
    if (p >= P_CNT) break;

    // load this patch's 72 inputs into registers (coalesced float4, 48B/lane stride)
    float4 x[18];
    #pragma unroll
    for (int c = 0; c < CINX; ++c) {
      const float4* xp = reinterpret_cast<const float4*>(rows[c] + p * PATCHSZ);
      x[c * 3 + 0] = xp[0];
      x[c * 3 + 1] = xp[1];
      x[c * 3 + 2] = xp[2];
    }

    for (int oi = 0; oi < 24; ++oi) {
      const int o = obase + oi;
      const float* wp = sw + o * KDOT;
      float a0 = 0.f, a1 = 0.f, a2 = 0.f, a3 = 0.f;
      #pragma unroll
      for (int c = 0; c < CINX; ++c) {
        const float4 w0 = *reinterpret_cast<const float4*>(wp + c * PATCHSZ + 0);
        const float4 w1 = *reinterpret_cast<const float4*>(wp + c * PATCHSZ + 4);
        const float4 w2 = *reinterpret_cast<const float4*>(wp + c * PATCHSZ + 8);
        const float4 x0 = x[c * 3 + 0];
        const float4 x1 = x[c * 3 + 1];
        const float4 x2 = x[c * 3 + 2];
        a0 = fmaf(w0.x, x0.x, a0); a1 = fmaf(w0.y, x0.y, a1);
        a2 = fmaf(w0.z, x0.z, a2); a3 = fmaf(w0.w, x0.w, a3);
        a0 = fmaf(w1.x, x1.x, a0); a1 = fmaf(w1.y, x1.y, a1);
        a2 = fmaf(w1.z, x1.z, a2); a3 = fmaf(w1.w, x1.w, a3);
        a0 = fmaf(w2.x, x2.x, a0); a1 = fmaf(w2.y, x2.y, a1);
        a2 = fmaf(w2.z, x2.z, a2); a3 = fmaf(w2.w, x2.w, a3);
      }
      outbn[o * P_CNT + p] = ((a0 + a1) + (a2 + a3)) + sb[o];
    }
  }
}

// ---------------- launch ----------------
extern "C" void kernel_launch(void* const* d_in, const int* in_sizes, int n_in,
                              void* d_out, int out_size, void* d_ws, size_t ws_size,
                              hipStream_t stream) {
  const float* hist = (const float*)d_in[0];  // [4,1024,1,2016]
  const float* adj  = (const float*)d_in[1];  // [1024,1024]
  const float* wgt  = (const float*)d_in[2];  // [96,6,12]
  const float* bias = (const float*)d_in[3];  // [96]
  float* out = (float*)d_out;                 // [4,1024,96,168]
  int* sampled = (int*)d_ws;                  // [1024*5]

  sample_kernel<<<dim3(N_NODES * K_NEIGH), dim3(256), 0, stream>>>(adj, sampled);
  embed_kernel<<<dim3(4 * N_NODES), dim3(256), 0, stream>>>(hist, wgt, bias, sampled, out);
}